// Round 16
// baseline (224.987 us; speedup 1.0000x reference)
//
#include <hip/hip_runtime.h>
#include <hip/hip_bf16.h>

typedef __bf16 bf16;
typedef __bf16 bf16x4 __attribute__((ext_vector_type(4)));
typedef __bf16 bf16x8 __attribute__((ext_vector_type(8)));
typedef float f32x4 __attribute__((ext_vector_type(4)));

#define B_ 4
#define C_ 256
#define NH_ 4
#define KD_ 32
#define HD_ 64
#define N_ 4096
#define HQKV_ 512

// ---------------- prep: weight convert (192 elems/block) + x transpose ----------------
__global__ __launch_bounds__(256) void k_prep(const float* __restrict__ x,
                                              bf16* __restrict__ xT,
                                              const float* __restrict__ wq,
                                              const float* __restrict__ wp,
                                              bf16* __restrict__ wqb,
                                              bf16* __restrict__ wpb) {
    int t = threadIdx.x;
    int fid = (blockIdx.z * 4 + blockIdx.y) * 64 + blockIdx.x;
    if (t < 192) {
        int i = fid * 192 + t;
        if (i < HQKV_ * C_) wqb[i] = (bf16)wq[i];
        else                wpb[i - HQKV_ * C_] = (bf16)wp[i - HQKV_ * C_];
    }
    __shared__ float tile[64][65];
    int b = blockIdx.z, c0 = blockIdx.y * 64, n0 = blockIdx.x * 64;
    int lane = t & 63, wv = t >> 6;
    for (int k = 0; k < 16; ++k) {
        int cl = k * 4 + wv;
        tile[cl][lane] = x[((size_t)(b * C_ + c0 + cl)) * N_ + n0 + lane];
    }
    __syncthreads();
    for (int k = 0; k < 16; ++k) {
        int nl = k * 4 + wv;
        xT[((size_t)(b * N_ + n0 + nl)) * C_ + c0 + lane] = (bf16)tile[lane][nl];
    }
}

// ---------------- qkv GEMM: W(512x256) @ xT^T, writes q_t,k_t,(B,NH,N,32) v(B,NH,64,N) ----------------
__global__ __launch_bounds__(256) void k_qkv(const bf16* __restrict__ wqb,
                                             const bf16* __restrict__ xT,
                                             const float* __restrict__ bias,
                                             bf16* __restrict__ qt, bf16* __restrict__ kt,
                                             bf16* __restrict__ vb) {
    int n0 = blockIdx.x * 64, o0 = blockIdx.y * 64, b = blockIdx.z;
    int t = threadIdx.x, w = t >> 6, l = t & 63, lr = l & 15, lg = l >> 4;
    const bf16* arow = wqb + (size_t)(o0 + 16 * w + lr) * C_ + 8 * lg;
    const bf16* brow = xT + ((size_t)b * N_ + n0 + lr) * C_ + 8 * lg;
    f32x4 acc[4];
    f32x4 zz = {0.f, 0.f, 0.f, 0.f};
    acc[0] = zz; acc[1] = zz; acc[2] = zz; acc[3] = zz;
    for (int kk = 0; kk < C_; kk += 32) {
        bf16x8 a = *(const bf16x8*)(arow + kk);
#pragma unroll
        for (int tt = 0; tt < 4; ++tt) {
            bf16x8 bb = *(const bf16x8*)(brow + (size_t)tt * 16 * C_ + kk);
            acc[tt] = __builtin_amdgcn_mfma_f32_16x16x32_bf16(a, bb, acc[tt], 0, 0, 0);
        }
    }
    // KD^-0.5 * log2(e) folded into q so attention can use raw exp2
    const float scale = 0.25506953076085663f;
#pragma unroll
    for (int tt = 0; tt < 4; ++tt) {
        int n = n0 + 16 * tt + lr;
#pragma unroll
        for (int j = 0; j < 4; ++j) {
            int o = o0 + 16 * w + 4 * lg + j;
            float val = acc[tt][j] + bias[o];
            int h = o >> 7, r = o & 127;
            size_t bh = (size_t)(b * NH_ + h);
            if (r < KD_)            qt[(bh * N_ + n) * KD_ + r] = (bf16)(val * scale);
            else if (r < 2 * KD_)   kt[(bh * N_ + n) * KD_ + (r - KD_)] = (bf16)val;
            else                    vb[(bh * HD_ + (r - 2 * KD_)) * N_ + n] = (bf16)val;
        }
    }
}

// ---------------- fused flash attention + PE dwconv epilogue ----------------
// R12 core; 25.6KB LDS pool (red/vt alias dead K/V). launch_bounds (256,4):
// cap 128 VGPR >= 76 live (no spill; R14's (256,6) cap 85 spilled oacc).
// R7 evidence: (256,4) measured 35% occupancy vs 25% at (256,3).
__global__ __launch_bounds__(256, 4) void k_attn(const bf16* __restrict__ qt,
                                                 const bf16* __restrict__ kt,
                                                 const bf16* __restrict__ vb,
                                                 const float* __restrict__ wpe,
                                                 const float* __restrict__ bpe,
                                                 bf16* __restrict__ yT) {
    __shared__ __align__(16) char pool[25600];
    bf16* ldsK = (bf16*)pool;               // 2 × 64×32 bf16 = 8KB
    bf16* ldsV = (bf16*)(pool + 8192);      // 2 × 64×64 bf16 = 16KB
    float* red = (float*)pool;              // 16KB epilogue reduction (aliases K/V)
    bf16* vt   = (bf16*)pool;               // 25.6KB epilogue v window (aliases all)
    int id = blockIdx.x;
    int bh = id & 15;            // id%8 == bh%8 -> 2 heads' K/V per XCD L2
    int n0 = (id >> 4) * 64;
    int hh = id >> 4;
    int b = bh >> 2, h = bh & 3;
    int t = threadIdx.x, w = t >> 6, l = t & 63, lr = l & 15, lg = l >> 4;

    bf16x8 aq[4];
#pragma unroll
    for (int f = 0; f < 4; ++f)
        aq[f] = *(const bf16x8*)(qt + ((size_t)bh * N_ + n0 + 16 * f + lr) * KD_ + 8 * lg);

    // staging: wave w stages K rows [16w,16w+16), V rows [16w,16w+16)
    int krow = 16 * w + (l >> 2);
    const bf16* kg = kt + ((size_t)bh * N_ + krow) * KD_ + 8 * (l & 3);
    int fkr = (krow ^ (krow >> 2)) & 3;
    int kwo = krow * KD_ + 8 * ((l & 3) ^ fkr);
    int vrow0 = 16 * w + (l >> 3), vrow1 = vrow0 + 8;
    const bf16* vg0 = vb + ((size_t)bh * HD_ + vrow0) * N_ + 8 * (l & 7);
    const bf16* vg1 = vb + ((size_t)bh * HD_ + vrow1) * N_ + 8 * (l & 7);
    int vwo0 = vrow0 * 64 + 8 * ((l & 7) ^ (vrow0 & 7));
    int vwo1 = vrow1 * 64 + 8 * ((l & 7) ^ (vrow1 & 7));

    // read offsets (wave-local slices)
    int kro = (16 * w + lr) * KD_ + 8 * (lg ^ ((lr ^ (lr >> 2)) & 3));
    int vro = 8 * ((2 * w + (lg >> 1)) ^ (lr & 7)) + 4 * ((lg & 1) ^ ((lr >> 3) & 1));

    f32x4 zz = {0.f, 0.f, 0.f, 0.f};
    f32x4 oacc[4][4];
#pragma unroll
    for (int f = 0; f < 4; ++f)
#pragma unroll
        for (int dt = 0; dt < 4; ++dt) oacc[f][dt] = zz;
    float Lp[4] = {0.f, 0.f, 0.f, 0.f};

    bf16x8 rk  = *(const bf16x8*)(kg);
    bf16x8 rv0 = *(const bf16x8*)(vg0);
    bf16x8 rv1 = *(const bf16x8*)(vg1);

    int cur = 0;
    for (int m0 = 0; m0 < N_; m0 += 64, cur ^= 1) {
        *(bf16x8*)(ldsK + cur * (64 * KD_) + kwo) = rk;
        *(bf16x8*)(ldsV + cur * (64 * 64) + vwo0) = rv0;
        *(bf16x8*)(ldsV + cur * (64 * 64) + vwo1) =
            __builtin_shufflevector(rv1, rv1, 4, 5, 6, 7, 0, 1, 2, 3);  // half-swap (d bit3=1)
        if (m0 + 64 < N_) {
            rk  = *(const bf16x8*)(kg + (size_t)(m0 + 64) * KD_);
            rv0 = *(const bf16x8*)(vg0 + m0 + 64);
            rv1 = *(const bf16x8*)(vg1 + m0 + 64);
        }
        __syncthreads();
        bf16x8 kf = *(const bf16x8*)(ldsK + cur * (64 * KD_) + kro);
        bf16x4 vf[4];
#pragma unroll
        for (int dt = 0; dt < 4; ++dt)
            vf[dt] = *(const bf16x4*)(ldsV + cur * (64 * 64) + (16 * dt + lr) * 64 + vro);
#pragma unroll
        for (int f = 0; f < 4; ++f) {
            f32x4 s = __builtin_amdgcn_mfma_f32_16x16x32_bf16(kf, aq[f], zz, 0, 0, 0);
            f32x4 p;
#pragma unroll
            for (int j = 0; j < 4; ++j) p[j] = __builtin_amdgcn_exp2f(s[j]);
            Lp[f] += (p[0] + p[1]) + (p[2] + p[3]);
            bf16x4 pk;
#pragma unroll
            for (int j = 0; j < 4; ++j) pk[j] = (bf16)p[j];
#pragma unroll
            for (int dt = 0; dt < 4; ++dt)
                asm("s_nop 1\n\tv_mfma_f32_16x16x16_bf16 %0, %1, %2, %0"
                    : "+v"(oacc[f][dt]) : "v"(pk), "v"(vf[dt]));
        }
    }
    // MFMA(asm) -> VALU/LDS read hazard guard
    asm volatile("s_nop 7\n\ts_nop 7\n\ts_nop 7" ::: "memory");
    __syncthreads();   // guard: red aliases K/V — all waves done with main loop

    // ---- L reduce: over lg (shfl), then over waves (LDS) ----
#pragma unroll
    for (int f = 0; f < 4; ++f) {
        Lp[f] += __shfl_xor(Lp[f], 16);
        Lp[f] += __shfl_xor(Lp[f], 32);
    }
    if (lg == 0) {
#pragma unroll
        for (int f = 0; f < 4; ++f) red[w * 64 + 16 * f + lr] = Lp[f];
    }
    __syncthreads();
    float invL[4];
#pragma unroll
    for (int f = 0; f < 4; ++f) {
        float Lt = red[16 * f + lr] + red[64 + 16 * f + lr] +
                   red[128 + 16 * f + lr] + red[192 + 16 * f + lr];
        invL[f] = 1.f / Lt;
    }
    __syncthreads();

    // ---- O cross-wave reduce: 4 static passes over dt; register indices static ----
    f32x4 ofin[4];
#pragma unroll
    for (int f = 0; f < 4; ++f) ofin[f] = zz;
#pragma unroll
    for (int dt = 0; dt < 4; ++dt) {
#pragma unroll
        for (int f = 0; f < 4; ++f)
#pragma unroll
            for (int j = 0; j < 4; ++j)
                red[w * 1024 + (16 * f + 4 * lg + j) * 16 + lr] = oacc[f][dt][j];
        __syncthreads();
        if (w == dt) {
#pragma unroll
            for (int f = 0; f < 4; ++f)
#pragma unroll
                for (int j = 0; j < 4; ++j) {
                    int idx = (16 * f + 4 * lg + j) * 16 + lr;
                    ofin[f][j] = red[idx] + red[1024 + idx] + red[2048 + idx] + red[3072 + idx];
                }
        }
        __syncthreads();
    }

    // ---- fused PE: stage v window (rows hh-1..hh+1, 64 ch) into vt, stride 200 ----
    {
        bf16x8 zero8 = {};
#pragma unroll
        for (int i = 0; i < 6; ++i) {
            int pair = (t >> 3) + 32 * i;     // 0..191
            int d = pair & 63, kh = pair >> 6;
            int hh2 = hh + kh - 1;
            bf16x8 val = zero8;
            if (hh2 >= 0 && hh2 < 64)
                val = *(const bf16x8*)(vb + ((size_t)bh * HD_ + d) * N_ + hh2 * 64 + (t & 7) * 8);
            *(bf16x8*)(vt + d * 200 + kh * 64 + (t & 7) * 8) = val;
        }
    }
    __syncthreads();

    // ---- conv + normalize + store: thread owns d=16w+lr, n = n0 + 16f + 4lg + j ----
    int dloc = 16 * w + lr;
    int c = h * 64 + dloc;
    float w9[9];
#pragma unroll
    for (int k = 0; k < 9; ++k) w9[k] = wpe[c * 9 + k];
    float bc = bpe[c];
#pragma unroll
    for (int f = 0; f < 4; ++f) {
        float conv[4] = {bc, bc, bc, bc};
#pragma unroll
        for (int kh = 0; kh < 3; ++kh) {
            float tv[6];
#pragma unroll
            for (int s = 0; s < 6; ++s) {
                int q = 16 * f + 4 * lg - 1 + s;
                tv[s] = (q >= 0 && q < 64) ? (float)vt[dloc * 200 + kh * 64 + q] : 0.f;
            }
#pragma unroll
            for (int j = 0; j < 4; ++j)
                conv[j] += tv[j] * w9[kh * 3] + tv[j + 1] * w9[kh * 3 + 1] + tv[j + 2] * w9[kh * 3 + 2];
        }
#pragma unroll
        for (int j = 0; j < 4; ++j) {
            float iv = __shfl(invL[f], 4 * lg + j);
            int n = n0 + 16 * f + 4 * lg + j;
            yT[((size_t)b * N_ + n) * C_ + c] = (bf16)(ofin[f][j] * iv + conv[j]);
        }
    }
}

// ---------------- proj GEMM + residual -> x2 (bf16) + fused CA partial sum/max ----------------
__global__ __launch_bounds__(256) void k_proj(const bf16* __restrict__ wpb,
                                              const bf16* __restrict__ yT,
                                              const float* __restrict__ bias,
                                              const float* __restrict__ x,
                                              bf16* __restrict__ x2,
                                              float* __restrict__ psum,
                                              float* __restrict__ pmax) {
    int n0 = blockIdx.x * 64, o0 = blockIdx.y * 64, b = blockIdx.z;
    int t = threadIdx.x, w = t >> 6, l = t & 63, lr = l & 15, lg = l >> 4;
    const bf16* arow = wpb + (size_t)(o0 + 16 * w + lr) * C_ + 8 * lg;
    const bf16* brow = yT + ((size_t)b * N_ + n0 + lr) * C_ + 8 * lg;
    f32x4 acc[4];
    f32x4 zz = {0.f, 0.f, 0.f, 0.f};
    acc[0] = zz; acc[1] = zz; acc[2] = zz; acc[3] = zz;
    for (int kk = 0; kk < C_; kk += 32) {
        bf16x8 a = *(const bf16x8*)(arow + kk);
#pragma unroll
        for (int tt = 0; tt < 4; ++tt) {
            bf16x8 bb = *(const bf16x8*)(brow + (size_t)tt * 16 * C_ + kk);
            acc[tt] = __builtin_amdgcn_mfma_f32_16x16x32_bf16(a, bb, acc[tt], 0, 0, 0);
        }
    }
    float lsum[4] = {0.f, 0.f, 0.f, 0.f};
    float lmax[4] = {-1e30f, -1e30f, -1e30f, -1e30f};
#pragma unroll
    for (int tt = 0; tt < 4; ++tt) {
        int n = n0 + 16 * tt + lr;
#pragma unroll
        for (int j = 0; j < 4; ++j) {
            int o = o0 + 16 * w + 4 * lg + j;
            size_t idx = ((size_t)b * C_ + o) * N_ + n;
            float v = x[idx] + acc[tt][j] + bias[o];
            x2[idx] = (bf16)v;
            lsum[j] += v;
            lmax[j] = fmaxf(lmax[j], v);
        }
    }
#pragma unroll
    for (int d = 1; d < 16; d <<= 1) {
#pragma unroll
        for (int j = 0; j < 4; ++j) {
            lsum[j] += __shfl_xor(lsum[j], d);
            lmax[j] = fmaxf(lmax[j], __shfl_xor(lmax[j], d));
        }
    }
    if (lr == 0) {
#pragma unroll
        for (int j = 0; j < 4; ++j) {
            int o = o0 + 16 * w + 4 * lg + j;
            size_t pidx = ((size_t)(b * C_ + o)) * 64 + blockIdx.x;
            psum[pidx] = lsum[j];
            pmax[pidx] = lmax[j];
        }
    }
}

// ---------------- channel attention finish: reduce partials + MLP + sigmoid ----------------
__global__ __launch_bounds__(256) void k_ca_fin(const float* __restrict__ psum,
                                                const float* __restrict__ pmax,
                                                const float* __restrict__ wfc1,
                                                const float* __restrict__ wfc2,
                                                float* __restrict__ ca) {
    int b = blockIdx.x, t = threadIdx.x;  // t = channel
    const float* ps = psum + ((size_t)(b * C_ + t)) * 64;
    const float* pm = pmax + ((size_t)(b * C_ + t)) * 64;
    float s = 0.f, m = -1e30f;
#pragma unroll 8
    for (int i = 0; i < 64; ++i) { s += ps[i]; m = fmaxf(m, pm[i]); }
    __shared__ float sav[C_], smx[C_];
    sav[t] = s * (1.f / (float)N_);
    smx[t] = m;
    __syncthreads();
    __shared__ float hsum[16];
    if (t < 16) {
        const float* w1 = wfc1 + t * C_;
        float ha = 0.f, hm = 0.f;
        for (int c = 0; c < C_; ++c) { ha += sav[c] * w1[c]; hm += smx[c] * w1[c]; }
        hsum[t] = fmaxf(ha, 0.f) + fmaxf(hm, 0.f);
    }
    __syncthreads();
    float o = 0.f;
    const float* w2 = wfc2 + t * 16;
#pragma unroll
    for (int r = 0; r < 16; ++r) o += hsum[r] * w2[r];
    ca[b * C_ + t] = 1.f / (1.f + __expf(-o));
}

// ---------------- spatial attention: channel reduce of x2*ca, 4-way c-split ----------------
__global__ __launch_bounds__(256) void k_sa_red(const bf16* __restrict__ x2,
                                                const float* __restrict__ ca,
                                                float* __restrict__ sain) {
    int b = blockIdx.y;
    int n0 = blockIdx.x * 64;
    int t = threadIdx.x, nl = t & 63, cg = t >> 6;
    __shared__ float cal[C_];
    cal[t] = ca[b * C_ + t];
    __syncthreads();
    int n = n0 + nl;
    float s = 0.f, m = -1e30f;
#pragma unroll 8
    for (int ci = 0; ci < 64; ++ci) {
        int c = cg * 64 + ci;
        float v = (float)x2[((size_t)b * C_ + c) * N_ + n] * cal[c];
        s += v; m = fmaxf(m, v);
    }
    __shared__ float ps[4][64], pm[4][64];
    ps[cg][nl] = s; pm[cg][nl] = m;
    __syncthreads();
    if (t < 64) {
        float ss = ps[0][t] + ps[1][t] + ps[2][t] + ps[3][t];
        float mm = fmaxf(fmaxf(pm[0][t], pm[1][t]), fmaxf(pm[2][t], pm[3][t]));
        sain[((size_t)b * 2 + 0) * N_ + n0 + t] = ss * (1.f / C_);
        sain[((size_t)b * 2 + 1) * N_ + n0 + t] = mm;
    }
}

// ---------------- final: sa conv + sigmoid + output (f32), 4-way c-split ----------------
__global__ __launch_bounds__(256) void k_final(const bf16* __restrict__ x2,
                                               const float* __restrict__ ca,
                                               const float* __restrict__ sain,
                                               const float* __restrict__ wsa,
                                               float* __restrict__ out) {
    int b = blockIdx.z;
    int c0 = blockIdx.y * 64;
    int n = blockIdx.x * 256 + threadIdx.x;
    __shared__ float cal[64];
    if (threadIdx.x < 64) cal[threadIdx.x] = ca[b * C_ + c0 + threadIdx.x];
    __syncthreads();
    int hh = n >> 6, ww = n & 63;
    float acc = 0.f;
#pragma unroll
    for (int i = 0; i < 2; ++i)
#pragma unroll
        for (int kh = 0; kh < 3; ++kh) {
            int hh2 = hh + kh - 1;
            if (hh2 < 0 || hh2 >= 64) continue;
#pragma unroll
            for (int kw = 0; kw < 3; ++kw) {
                int ww2 = ww + kw - 1;
                if (ww2 < 0 || ww2 >= 64) continue;
                acc += sain[((size_t)b * 2 + i) * N_ + hh2 * 64 + ww2] * wsa[i * 9 + kh * 3 + kw];
            }
        }
    float sa = 1.f / (1.f + __expf(-acc));
#pragma unroll 8
    for (int ci = 0; ci < 64; ++ci) {
        int c = c0 + ci;
        size_t idx = ((size_t)b * C_ + c) * N_ + n;
        out[idx] = (float)x2[idx] * cal[ci] * sa;
    }
}

extern "C" void kernel_launch(void* const* d_in, const int* in_sizes, int n_in,
                              void* d_out, int out_size, void* d_ws, size_t ws_size,
                              hipStream_t stream) {
    const float* x     = (const float*)d_in[0];
    const float* wqkv  = (const float*)d_in[1];
    const float* bqkv  = (const float*)d_in[2];
    const float* wproj = (const float*)d_in[3];
    const float* bproj = (const float*)d_in[4];
    const float* wpe   = (const float*)d_in[5];
    const float* bpe   = (const float*)d_in[6];
    const float* wfc1  = (const float*)d_in[7];
    const float* wfc2  = (const float*)d_in[8];
    const float* wsa   = (const float*)d_in[9];
    float* out = (float*)d_out;

    char* ws = (char*)d_ws;
    size_t off = 0;
    auto alloc = [&](size_t bytes) {
        char* p = ws + off;
        off += (bytes + 255) & ~(size_t)255;
        return p;
    };
    bf16*  qt    = (bf16*)alloc((size_t)B_ * NH_ * N_ * KD_ * 2);
    bf16*  ktb   = (bf16*)alloc((size_t)B_ * NH_ * N_ * KD_ * 2);
    bf16*  vbuf  = (bf16*)alloc((size_t)B_ * NH_ * HD_ * N_ * 2);
    bf16*  xT    = (bf16*)alloc((size_t)B_ * N_ * C_ * 2);
    bf16*  x2    = (bf16*)alloc((size_t)B_ * C_ * N_ * 2);
    bf16*  wqb   = (bf16*)alloc((size_t)HQKV_ * C_ * 2);
    bf16*  wpb   = (bf16*)alloc((size_t)C_ * C_ * 2);
    float* psum  = (float*)alloc((size_t)B_ * C_ * 64 * 4);
    float* pmax  = (float*)alloc((size_t)B_ * C_ * 64 * 4);
    float* cab   = (float*)alloc(B_ * C_ * 4);
    float* sain  = (float*)alloc((size_t)B_ * 2 * N_ * 4);
    bf16*  yT    = xT;  // alias: xT dead after k_qkv completes (stream-ordered)

    k_prep<<<dim3(64, 4, B_), 256, 0, stream>>>(x, xT, wqkv, wproj, wqb, wpb);
    k_qkv<<<dim3(64, 8, B_), 256, 0, stream>>>(wqb, xT, bqkv, qt, ktb, vbuf);
    k_attn<<<dim3(1024), 256, 0, stream>>>(qt, ktb, vbuf, wpe, bpe, yT);
    k_proj<<<dim3(64, 4, B_), 256, 0, stream>>>(wpb, yT, bproj, x, x2, psum, pmax);
    k_ca_fin<<<dim3(B_), 256, 0, stream>>>(psum, pmax, wfc1, wfc2, cab);
    k_sa_red<<<dim3(64, B_), 256, 0, stream>>>(x2, cab, sain);
    k_final<<<dim3(16, 4, B_), 256, 0, stream>>>(x2, cab, sain, wsa, out);
}

// Round 17
// 192.482 us; speedup vs baseline: 1.1689x; 1.1689x over previous
//
#include <hip/hip_runtime.h>
#include <hip/hip_bf16.h>

typedef __bf16 bf16;
typedef __bf16 bf16x4 __attribute__((ext_vector_type(4)));
typedef __bf16 bf16x8 __attribute__((ext_vector_type(8)));
typedef float f32x4 __attribute__((ext_vector_type(4)));

#define B_ 4
#define C_ 256
#define NH_ 4
#define KD_ 32
#define HD_ 64
#define N_ 4096
#define HQKV_ 512

// ---------------- prep: weight convert (192 elems/block) + x transpose ----------------
__global__ __launch_bounds__(256) void k_prep(const float* __restrict__ x,
                                              bf16* __restrict__ xT,
                                              const float* __restrict__ wq,
                                              const float* __restrict__ wp,
                                              bf16* __restrict__ wqb,
                                              bf16* __restrict__ wpb) {
    int t = threadIdx.x;
    int fid = (blockIdx.z * 4 + blockIdx.y) * 64 + blockIdx.x;
    if (t < 192) {
        int i = fid * 192 + t;
        if (i < HQKV_ * C_) wqb[i] = (bf16)wq[i];
        else                wpb[i - HQKV_ * C_] = (bf16)wp[i - HQKV_ * C_];
    }
    __shared__ float tile[64][65];
    int b = blockIdx.z, c0 = blockIdx.y * 64, n0 = blockIdx.x * 64;
    int lane = t & 63, wv = t >> 6;
    for (int k = 0; k < 16; ++k) {
        int cl = k * 4 + wv;
        tile[cl][lane] = x[((size_t)(b * C_ + c0 + cl)) * N_ + n0 + lane];
    }
    __syncthreads();
    for (int k = 0; k < 16; ++k) {
        int nl = k * 4 + wv;
        xT[((size_t)(b * N_ + n0 + nl)) * C_ + c0 + lane] = (bf16)tile[lane][nl];
    }
}

// ---------------- qkv GEMM: W(512x256) @ xT^T, writes q_t,k_t,(B,NH,N,32) v(B,NH,64,N) ----------------
__global__ __launch_bounds__(256) void k_qkv(const bf16* __restrict__ wqb,
                                             const bf16* __restrict__ xT,
                                             const float* __restrict__ bias,
                                             bf16* __restrict__ qt, bf16* __restrict__ kt,
                                             bf16* __restrict__ vb) {
    int n0 = blockIdx.x * 64, o0 = blockIdx.y * 64, b = blockIdx.z;
    int t = threadIdx.x, w = t >> 6, l = t & 63, lr = l & 15, lg = l >> 4;
    const bf16* arow = wqb + (size_t)(o0 + 16 * w + lr) * C_ + 8 * lg;
    const bf16* brow = xT + ((size_t)b * N_ + n0 + lr) * C_ + 8 * lg;
    f32x4 acc[4];
    f32x4 zz = {0.f, 0.f, 0.f, 0.f};
    acc[0] = zz; acc[1] = zz; acc[2] = zz; acc[3] = zz;
    for (int kk = 0; kk < C_; kk += 32) {
        bf16x8 a = *(const bf16x8*)(arow + kk);
#pragma unroll
        for (int tt = 0; tt < 4; ++tt) {
            bf16x8 bb = *(const bf16x8*)(brow + (size_t)tt * 16 * C_ + kk);
            acc[tt] = __builtin_amdgcn_mfma_f32_16x16x32_bf16(a, bb, acc[tt], 0, 0, 0);
        }
    }
    // KD^-0.5 * log2(e) folded into q so attention can use raw exp2
    const float scale = 0.25506953076085663f;
#pragma unroll
    for (int tt = 0; tt < 4; ++tt) {
        int n = n0 + 16 * tt + lr;
#pragma unroll
        for (int j = 0; j < 4; ++j) {
            int o = o0 + 16 * w + 4 * lg + j;
            float val = acc[tt][j] + bias[o];
            int h = o >> 7, r = o & 127;
            size_t bh = (size_t)(b * NH_ + h);
            if (r < KD_)            qt[(bh * N_ + n) * KD_ + r] = (bf16)(val * scale);
            else if (r < 2 * KD_)   kt[(bh * N_ + n) * KD_ + (r - KD_)] = (bf16)val;
            else                    vb[(bh * HD_ + (r - 2 * KD_)) * N_ + n] = (bf16)val;
        }
    }
}

// ---------------- fused flash attention + PE dwconv epilogue ----------------
// R15 core at (256,3) — natural VGPR ~76, no spill (bounds >=4 all spilled:
// R11/R14/R16). Change vs R15: the 4 PV MFMAs per f merged into ONE asm block
// (one s_nop guard instead of four; back-to-back MFMA issue). All 9 operands
// already live — no added register pressure.
__global__ __launch_bounds__(256, 3) void k_attn(const bf16* __restrict__ qt,
                                                 const bf16* __restrict__ kt,
                                                 const bf16* __restrict__ vb,
                                                 const float* __restrict__ wpe,
                                                 const float* __restrict__ bpe,
                                                 bf16* __restrict__ yT) {
    __shared__ __align__(16) char pool[25600];
    bf16* ldsK = (bf16*)pool;               // 2 × 64×32 bf16 = 8KB
    bf16* ldsV = (bf16*)(pool + 8192);      // 2 × 64×64 bf16 = 16KB
    float* red = (float*)pool;              // 16KB epilogue reduction (aliases K/V)
    bf16* vt   = (bf16*)pool;               // 25.6KB epilogue v window (aliases all)
    int id = blockIdx.x;
    int bh = id & 15;            // id%8 == bh%8 -> 2 heads' K/V per XCD L2
    int n0 = (id >> 4) * 64;
    int hh = id >> 4;
    int b = bh >> 2, h = bh & 3;
    int t = threadIdx.x, w = t >> 6, l = t & 63, lr = l & 15, lg = l >> 4;

    bf16x8 aq[4];
#pragma unroll
    for (int f = 0; f < 4; ++f)
        aq[f] = *(const bf16x8*)(qt + ((size_t)bh * N_ + n0 + 16 * f + lr) * KD_ + 8 * lg);

    // staging: wave w stages K rows [16w,16w+16), V rows [16w,16w+16)
    int krow = 16 * w + (l >> 2);
    const bf16* kg = kt + ((size_t)bh * N_ + krow) * KD_ + 8 * (l & 3);
    int fkr = (krow ^ (krow >> 2)) & 3;
    int kwo = krow * KD_ + 8 * ((l & 3) ^ fkr);
    int vrow0 = 16 * w + (l >> 3), vrow1 = vrow0 + 8;
    const bf16* vg0 = vb + ((size_t)bh * HD_ + vrow0) * N_ + 8 * (l & 7);
    const bf16* vg1 = vb + ((size_t)bh * HD_ + vrow1) * N_ + 8 * (l & 7);
    int vwo0 = vrow0 * 64 + 8 * ((l & 7) ^ (vrow0 & 7));
    int vwo1 = vrow1 * 64 + 8 * ((l & 7) ^ (vrow1 & 7));

    // read offsets (wave-local slices)
    int kro = (16 * w + lr) * KD_ + 8 * (lg ^ ((lr ^ (lr >> 2)) & 3));
    int vro = 8 * ((2 * w + (lg >> 1)) ^ (lr & 7)) + 4 * ((lg & 1) ^ ((lr >> 3) & 1));

    f32x4 zz = {0.f, 0.f, 0.f, 0.f};
    f32x4 oacc[4][4];
#pragma unroll
    for (int f = 0; f < 4; ++f)
#pragma unroll
        for (int dt = 0; dt < 4; ++dt) oacc[f][dt] = zz;
    float Lp[4] = {0.f, 0.f, 0.f, 0.f};

    bf16x8 rk  = *(const bf16x8*)(kg);
    bf16x8 rv0 = *(const bf16x8*)(vg0);
    bf16x8 rv1 = *(const bf16x8*)(vg1);

    int cur = 0;
    for (int m0 = 0; m0 < N_; m0 += 64, cur ^= 1) {
        *(bf16x8*)(ldsK + cur * (64 * KD_) + kwo) = rk;
        *(bf16x8*)(ldsV + cur * (64 * 64) + vwo0) = rv0;
        *(bf16x8*)(ldsV + cur * (64 * 64) + vwo1) =
            __builtin_shufflevector(rv1, rv1, 4, 5, 6, 7, 0, 1, 2, 3);  // half-swap (d bit3=1)
        if (m0 + 64 < N_) {
            rk  = *(const bf16x8*)(kg + (size_t)(m0 + 64) * KD_);
            rv0 = *(const bf16x8*)(vg0 + m0 + 64);
            rv1 = *(const bf16x8*)(vg1 + m0 + 64);
        }
        __syncthreads();
        bf16x8 kf = *(const bf16x8*)(ldsK + cur * (64 * KD_) + kro);
        bf16x4 vf[4];
#pragma unroll
        for (int dt = 0; dt < 4; ++dt)
            vf[dt] = *(const bf16x4*)(ldsV + cur * (64 * 64) + (16 * dt + lr) * 64 + vro);
#pragma unroll
        for (int f = 0; f < 4; ++f) {
            f32x4 s = __builtin_amdgcn_mfma_f32_16x16x32_bf16(kf, aq[f], zz, 0, 0, 0);
            f32x4 p;
#pragma unroll
            for (int j = 0; j < 4; ++j) p[j] = __builtin_amdgcn_exp2f(s[j]);
            Lp[f] += (p[0] + p[1]) + (p[2] + p[3]);
            bf16x4 pk;
#pragma unroll
            for (int j = 0; j < 4; ++j) pk[j] = (bf16)p[j];
            asm("s_nop 1\n\t"
                "v_mfma_f32_16x16x16_bf16 %0, %4, %5, %0\n\t"
                "v_mfma_f32_16x16x16_bf16 %1, %4, %6, %1\n\t"
                "v_mfma_f32_16x16x16_bf16 %2, %4, %7, %2\n\t"
                "v_mfma_f32_16x16x16_bf16 %3, %4, %8, %3"
                : "+v"(oacc[f][0]), "+v"(oacc[f][1]), "+v"(oacc[f][2]), "+v"(oacc[f][3])
                : "v"(pk), "v"(vf[0]), "v"(vf[1]), "v"(vf[2]), "v"(vf[3]));
        }
    }
    // MFMA(asm) -> VALU/LDS read hazard guard
    asm volatile("s_nop 7\n\ts_nop 7\n\ts_nop 7" ::: "memory");
    __syncthreads();   // guard: red aliases K/V — all waves done with main loop

    // ---- L reduce: over lg (shfl), then over waves (LDS) ----
#pragma unroll
    for (int f = 0; f < 4; ++f) {
        Lp[f] += __shfl_xor(Lp[f], 16);
        Lp[f] += __shfl_xor(Lp[f], 32);
    }
    if (lg == 0) {
#pragma unroll
        for (int f = 0; f < 4; ++f) red[w * 64 + 16 * f + lr] = Lp[f];
    }
    __syncthreads();
    float invL[4];
#pragma unroll
    for (int f = 0; f < 4; ++f) {
        float Lt = red[16 * f + lr] + red[64 + 16 * f + lr] +
                   red[128 + 16 * f + lr] + red[192 + 16 * f + lr];
        invL[f] = 1.f / Lt;
    }
    __syncthreads();

    // ---- O cross-wave reduce: 4 static passes over dt; register indices static ----
    f32x4 ofin[4];
#pragma unroll
    for (int f = 0; f < 4; ++f) ofin[f] = zz;
#pragma unroll
    for (int dt = 0; dt < 4; ++dt) {
#pragma unroll
        for (int f = 0; f < 4; ++f)
#pragma unroll
            for (int j = 0; j < 4; ++j)
                red[w * 1024 + (16 * f + 4 * lg + j) * 16 + lr] = oacc[f][dt][j];
        __syncthreads();
        if (w == dt) {
#pragma unroll
            for (int f = 0; f < 4; ++f)
#pragma unroll
                for (int j = 0; j < 4; ++j) {
                    int idx = (16 * f + 4 * lg + j) * 16 + lr;
                    ofin[f][j] = red[idx] + red[1024 + idx] + red[2048 + idx] + red[3072 + idx];
                }
        }
        __syncthreads();
    }

    // ---- fused PE: stage v window (rows hh-1..hh+1, 64 ch) into vt, stride 200 ----
    {
        bf16x8 zero8 = {};
#pragma unroll
        for (int i = 0; i < 6; ++i) {
            int pair = (t >> 3) + 32 * i;     // 0..191
            int d = pair & 63, kh = pair >> 6;
            int hh2 = hh + kh - 1;
            bf16x8 val = zero8;
            if (hh2 >= 0 && hh2 < 64)
                val = *(const bf16x8*)(vb + ((size_t)bh * HD_ + d) * N_ + hh2 * 64 + (t & 7) * 8);
            *(bf16x8*)(vt + d * 200 + kh * 64 + (t & 7) * 8) = val;
        }
    }
    __syncthreads();

    // ---- conv + normalize + store: thread owns d=16w+lr, n = n0 + 16f + 4lg + j ----
    int dloc = 16 * w + lr;
    int c = h * 64 + dloc;
    float w9[9];
#pragma unroll
    for (int k = 0; k < 9; ++k) w9[k] = wpe[c * 9 + k];
    float bc = bpe[c];
#pragma unroll
    for (int f = 0; f < 4; ++f) {
        float conv[4] = {bc, bc, bc, bc};
#pragma unroll
        for (int kh = 0; kh < 3; ++kh) {
            float tv[6];
#pragma unroll
            for (int s = 0; s < 6; ++s) {
                int q = 16 * f + 4 * lg - 1 + s;
                tv[s] = (q >= 0 && q < 64) ? (float)vt[dloc * 200 + kh * 64 + q] : 0.f;
            }
#pragma unroll
            for (int j = 0; j < 4; ++j)
                conv[j] += tv[j] * w9[kh * 3] + tv[j + 1] * w9[kh * 3 + 1] + tv[j + 2] * w9[kh * 3 + 2];
        }
#pragma unroll
        for (int j = 0; j < 4; ++j) {
            float iv = __shfl(invL[f], 4 * lg + j);
            int n = n0 + 16 * f + 4 * lg + j;
            yT[((size_t)b * N_ + n) * C_ + c] = (bf16)(ofin[f][j] * iv + conv[j]);
        }
    }
}

// ---------------- proj GEMM + residual -> x2 (bf16) + fused CA partial sum/max ----------------
__global__ __launch_bounds__(256) void k_proj(const bf16* __restrict__ wpb,
                                              const bf16* __restrict__ yT,
                                              const float* __restrict__ bias,
                                              const float* __restrict__ x,
                                              bf16* __restrict__ x2,
                                              float* __restrict__ psum,
                                              float* __restrict__ pmax) {
    int n0 = blockIdx.x * 64, o0 = blockIdx.y * 64, b = blockIdx.z;
    int t = threadIdx.x, w = t >> 6, l = t & 63, lr = l & 15, lg = l >> 4;
    const bf16* arow = wpb + (size_t)(o0 + 16 * w + lr) * C_ + 8 * lg;
    const bf16* brow = yT + ((size_t)b * N_ + n0 + lr) * C_ + 8 * lg;
    f32x4 acc[4];
    f32x4 zz = {0.f, 0.f, 0.f, 0.f};
    acc[0] = zz; acc[1] = zz; acc[2] = zz; acc[3] = zz;
    for (int kk = 0; kk < C_; kk += 32) {
        bf16x8 a = *(const bf16x8*)(arow + kk);
#pragma unroll
        for (int tt = 0; tt < 4; ++tt) {
            bf16x8 bb = *(const bf16x8*)(brow + (size_t)tt * 16 * C_ + kk);
            acc[tt] = __builtin_amdgcn_mfma_f32_16x16x32_bf16(a, bb, acc[tt], 0, 0, 0);
        }
    }
    float lsum[4] = {0.f, 0.f, 0.f, 0.f};
    float lmax[4] = {-1e30f, -1e30f, -1e30f, -1e30f};
#pragma unroll
    for (int tt = 0; tt < 4; ++tt) {
        int n = n0 + 16 * tt + lr;
#pragma unroll
        for (int j = 0; j < 4; ++j) {
            int o = o0 + 16 * w + 4 * lg + j;
            size_t idx = ((size_t)b * C_ + o) * N_ + n;
            float v = x[idx] + acc[tt][j] + bias[o];
            x2[idx] = (bf16)v;
            lsum[j] += v;
            lmax[j] = fmaxf(lmax[j], v);
        }
    }
#pragma unroll
    for (int d = 1; d < 16; d <<= 1) {
#pragma unroll
        for (int j = 0; j < 4; ++j) {
            lsum[j] += __shfl_xor(lsum[j], d);
            lmax[j] = fmaxf(lmax[j], __shfl_xor(lmax[j], d));
        }
    }
    if (lr == 0) {
#pragma unroll
        for (int j = 0; j < 4; ++j) {
            int o = o0 + 16 * w + 4 * lg + j;
            size_t pidx = ((size_t)(b * C_ + o)) * 64 + blockIdx.x;
            psum[pidx] = lsum[j];
            pmax[pidx] = lmax[j];
        }
    }
}

// ---------------- channel attention finish: reduce partials + MLP + sigmoid ----------------
__global__ __launch_bounds__(256) void k_ca_fin(const float* __restrict__ psum,
                                                const float* __restrict__ pmax,
                                                const float* __restrict__ wfc1,
                                                const float* __restrict__ wfc2,
                                                float* __restrict__ ca) {
    int b = blockIdx.x, t = threadIdx.x;  // t = channel
    const float* ps = psum + ((size_t)(b * C_ + t)) * 64;
    const float* pm = pmax + ((size_t)(b * C_ + t)) * 64;
    float s = 0.f, m = -1e30f;
#pragma unroll 8
    for (int i = 0; i < 64; ++i) { s += ps[i]; m = fmaxf(m, pm[i]); }
    __shared__ float sav[C_], smx[C_];
    sav[t] = s * (1.f / (float)N_);
    smx[t] = m;
    __syncthreads();
    __shared__ float hsum[16];
    if (t < 16) {
        const float* w1 = wfc1 + t * C_;
        float ha = 0.f, hm = 0.f;
        for (int c = 0; c < C_; ++c) { ha += sav[c] * w1[c]; hm += smx[c] * w1[c]; }
        hsum[t] = fmaxf(ha, 0.f) + fmaxf(hm, 0.f);
    }
    __syncthreads();
    float o = 0.f;
    const float* w2 = wfc2 + t * 16;
#pragma unroll
    for (int r = 0; r < 16; ++r) o += hsum[r] * w2[r];
    ca[b * C_ + t] = 1.f / (1.f + __expf(-o));
}

// ---------------- spatial attention: channel reduce of x2*ca, 4-way c-split ----------------
__global__ __launch_bounds__(256) void k_sa_red(const bf16* __restrict__ x2,
                                                const float* __restrict__ ca,
                                                float* __restrict__ sain) {
    int b = blockIdx.y;
    int n0 = blockIdx.x * 64;
    int t = threadIdx.x, nl = t & 63, cg = t >> 6;
    __shared__ float cal[C_];
    cal[t] = ca[b * C_ + t];
    __syncthreads();
    int n = n0 + nl;
    float s = 0.f, m = -1e30f;
#pragma unroll 8
    for (int ci = 0; ci < 64; ++ci) {
        int c = cg * 64 + ci;
        float v = (float)x2[((size_t)b * C_ + c) * N_ + n] * cal[c];
        s += v; m = fmaxf(m, v);
    }
    __shared__ float ps[4][64], pm[4][64];
    ps[cg][nl] = s; pm[cg][nl] = m;
    __syncthreads();
    if (t < 64) {
        float ss = ps[0][t] + ps[1][t] + ps[2][t] + ps[3][t];
        float mm = fmaxf(fmaxf(pm[0][t], pm[1][t]), fmaxf(pm[2][t], pm[3][t]));
        sain[((size_t)b * 2 + 0) * N_ + n0 + t] = ss * (1.f / C_);
        sain[((size_t)b * 2 + 1) * N_ + n0 + t] = mm;
    }
}

// ---------------- final: sa conv + sigmoid + output (f32), 4-way c-split ----------------
__global__ __launch_bounds__(256) void k_final(const bf16* __restrict__ x2,
                                               const float* __restrict__ ca,
                                               const float* __restrict__ sain,
                                               const float* __restrict__ wsa,
                                               float* __restrict__ out) {
    int b = blockIdx.z;
    int c0 = blockIdx.y * 64;
    int n = blockIdx.x * 256 + threadIdx.x;
    __shared__ float cal[64];
    if (threadIdx.x < 64) cal[threadIdx.x] = ca[b * C_ + c0 + threadIdx.x];
    __syncthreads();
    int hh = n >> 6, ww = n & 63;
    float acc = 0.f;
#pragma unroll
    for (int i = 0; i < 2; ++i)
#pragma unroll
        for (int kh = 0; kh < 3; ++kh) {
            int hh2 = hh + kh - 1;
            if (hh2 < 0 || hh2 >= 64) continue;
#pragma unroll
            for (int kw = 0; kw < 3; ++kw) {
                int ww2 = ww + kw - 1;
                if (ww2 < 0 || ww2 >= 64) continue;
                acc += sain[((size_t)b * 2 + i) * N_ + hh2 * 64 + ww2] * wsa[i * 9 + kh * 3 + kw];
            }
        }
    float sa = 1.f / (1.f + __expf(-acc));
#pragma unroll 8
    for (int ci = 0; ci < 64; ++ci) {
        int c = c0 + ci;
        size_t idx = ((size_t)b * C_ + c) * N_ + n;
        out[idx] = (float)x2[idx] * cal[ci] * sa;
    }
}

extern "C" void kernel_launch(void* const* d_in, const int* in_sizes, int n_in,
                              void* d_out, int out_size, void* d_ws, size_t ws_size,
                              hipStream_t stream) {
    const float* x     = (const float*)d_in[0];
    const float* wqkv  = (const float*)d_in[1];
    const float* bqkv  = (const float*)d_in[2];
    const float* wproj = (const float*)d_in[3];
    const float* bproj = (const float*)d_in[4];
    const float* wpe   = (const float*)d_in[5];
    const float* bpe   = (const float*)d_in[6];
    const float* wfc1  = (const float*)d_in[7];
    const float* wfc2  = (const float*)d_in[8];
    const float* wsa   = (const float*)d_in[9];
    float* out = (float*)d_out;

    char* ws = (char*)d_ws;
    size_t off = 0;
    auto alloc = [&](size_t bytes) {
        char* p = ws + off;
        off += (bytes + 255) & ~(size_t)255;
        return p;
    };
    bf16*  qt    = (bf16*)alloc((size_t)B_ * NH_ * N_ * KD_ * 2);
    bf16*  ktb   = (bf16*)alloc((size_t)B_ * NH_ * N_ * KD_ * 2);
    bf16*  vbuf  = (bf16*)alloc((size_t)B_ * NH_ * HD_ * N_ * 2);
    bf16*  xT    = (bf16*)alloc((size_t)B_ * N_ * C_ * 2);
    bf16*  x2    = (bf16*)alloc((size_t)B_ * C_ * N_ * 2);
    bf16*  wqb   = (bf16*)alloc((size_t)HQKV_ * C_ * 2);
    bf16*  wpb   = (bf16*)alloc((size_t)C_ * C_ * 2);
    float* psum  = (float*)alloc((size_t)B_ * C_ * 64 * 4);
    float* pmax  = (float*)alloc((size_t)B_ * C_ * 64 * 4);
    float* cab   = (float*)alloc(B_ * C_ * 4);
    float* sain  = (float*)alloc((size_t)B_ * 2 * N_ * 4);
    bf16*  yT    = xT;  // alias: xT dead after k_qkv completes (stream-ordered)

    k_prep<<<dim3(64, 4, B_), 256, 0, stream>>>(x, xT, wqkv, wproj, wqb, wpb);
    k_qkv<<<dim3(64, 8, B_), 256, 0, stream>>>(wqb, xT, bqkv, qt, ktb, vbuf);
    k_attn<<<dim3(1024), 256, 0, stream>>>(qt, ktb, vbuf, wpe, bpe, yT);
    k_proj<<<dim3(64, 4, B_), 256, 0, stream>>>(wpb, yT, bproj, x, x2, psum, pmax);
    k_ca_fin<<<dim3(B_), 256, 0, stream>>>(psum, pmax, wfc1, wfc2, cab);
    k_sa_red<<<dim3(64, B_), 256, 0, stream>>>(x2, cab, sain);
    k_final<<<dim3(16, 4, B_), 256, 0, stream>>>(x2, cab, sain, wsa, out);
}

// Round 18
// 190.926 us; speedup vs baseline: 1.1784x; 1.0081x over previous
//
#include <hip/hip_runtime.h>
#include <hip/hip_bf16.h>

typedef __bf16 bf16;
typedef __bf16 bf16x4 __attribute__((ext_vector_type(4)));
typedef __bf16 bf16x8 __attribute__((ext_vector_type(8)));
typedef float f32x4 __attribute__((ext_vector_type(4)));

#define B_ 4
#define C_ 256
#define NH_ 4
#define KD_ 32
#define HD_ 64
#define N_ 4096
#define HQKV_ 512

// ---------------- prep: weight convert (192 elems/block) + x transpose ----------------
__global__ __launch_bounds__(256) void k_prep(const float* __restrict__ x,
                                              bf16* __restrict__ xT,
                                              const float* __restrict__ wq,
                                              const float* __restrict__ wp,
                                              bf16* __restrict__ wqb,
                                              bf16* __restrict__ wpb) {
    int t = threadIdx.x;
    int fid = (blockIdx.z * 4 + blockIdx.y) * 64 + blockIdx.x;
    if (t < 192) {
        int i = fid * 192 + t;
        if (i < HQKV_ * C_) wqb[i] = (bf16)wq[i];
        else                wpb[i - HQKV_ * C_] = (bf16)wp[i - HQKV_ * C_];
    }
    __shared__ float tile[64][65];
    int b = blockIdx.z, c0 = blockIdx.y * 64, n0 = blockIdx.x * 64;
    int lane = t & 63, wv = t >> 6;
    for (int k = 0; k < 16; ++k) {
        int cl = k * 4 + wv;
        tile[cl][lane] = x[((size_t)(b * C_ + c0 + cl)) * N_ + n0 + lane];
    }
    __syncthreads();
    for (int k = 0; k < 16; ++k) {
        int nl = k * 4 + wv;
        xT[((size_t)(b * N_ + n0 + nl)) * C_ + c0 + lane] = (bf16)tile[lane][nl];
    }
}

// ---------------- qkv GEMM: W(512x256) @ xT^T, writes q_t,k_t,(B,NH,N,32) v(B,NH,64,N) ----------------
__global__ __launch_bounds__(256) void k_qkv(const bf16* __restrict__ wqb,
                                             const bf16* __restrict__ xT,
                                             const float* __restrict__ bias,
                                             bf16* __restrict__ qt, bf16* __restrict__ kt,
                                             bf16* __restrict__ vb) {
    int n0 = blockIdx.x * 64, o0 = blockIdx.y * 64, b = blockIdx.z;
    int t = threadIdx.x, w = t >> 6, l = t & 63, lr = l & 15, lg = l >> 4;
    const bf16* arow = wqb + (size_t)(o0 + 16 * w + lr) * C_ + 8 * lg;
    const bf16* brow = xT + ((size_t)b * N_ + n0 + lr) * C_ + 8 * lg;
    f32x4 acc[4];
    f32x4 zz = {0.f, 0.f, 0.f, 0.f};
    acc[0] = zz; acc[1] = zz; acc[2] = zz; acc[3] = zz;
    for (int kk = 0; kk < C_; kk += 32) {
        bf16x8 a = *(const bf16x8*)(arow + kk);
#pragma unroll
        for (int tt = 0; tt < 4; ++tt) {
            bf16x8 bb = *(const bf16x8*)(brow + (size_t)tt * 16 * C_ + kk);
            acc[tt] = __builtin_amdgcn_mfma_f32_16x16x32_bf16(a, bb, acc[tt], 0, 0, 0);
        }
    }
    // KD^-0.5 * log2(e) folded into q so attention can use raw exp2
    const float scale = 0.25506953076085663f;
#pragma unroll
    for (int tt = 0; tt < 4; ++tt) {
        int n = n0 + 16 * tt + lr;
#pragma unroll
        for (int j = 0; j < 4; ++j) {
            int o = o0 + 16 * w + 4 * lg + j;
            float val = acc[tt][j] + bias[o];
            int h = o >> 7, r = o & 127;
            size_t bh = (size_t)(b * NH_ + h);
            if (r < KD_)            qt[(bh * N_ + n) * KD_ + r] = (bf16)(val * scale);
            else if (r < 2 * KD_)   kt[(bh * N_ + n) * KD_ + (r - KD_)] = (bf16)val;
            else                    vb[(bh * HD_ + (r - 2 * KD_)) * N_ + n] = (bf16)val;
        }
    }
}

// ---------------- fused flash attention + PE dwconv epilogue ----------------
// R15 core at (256,3); change: m-step 128 — two 64-row half-tiles per barrier
// (32 barriers vs 64). Each half keeps the EXACT per-tile layout/swizzles of the
// proven 64-row tile; only the half base offset changes. Staging regs 3->6 bf16x8.
__global__ __launch_bounds__(256, 3) void k_attn(const bf16* __restrict__ qt,
                                                 const bf16* __restrict__ kt,
                                                 const bf16* __restrict__ vb,
                                                 const float* __restrict__ wpe,
                                                 const float* __restrict__ bpe,
                                                 bf16* __restrict__ yT) {
    __shared__ __align__(16) char pool[49152];
    // K: [parity][half][64*32] ; V: [parity][half][64*64]
    bf16* ldsK = (bf16*)pool;               // 16KB
    bf16* ldsV = (bf16*)(pool + 16384);     // 32KB
    float* red = (float*)pool;              // 16KB epilogue reduction (aliases K)
    bf16* vt   = (bf16*)pool;               // 25.6KB epilogue v window (aliases K/V)
    int id = blockIdx.x;
    int bh = id & 15;            // id%8 == bh%8 -> 2 heads' K/V per XCD L2
    int n0 = (id >> 4) * 64;
    int hh = id >> 4;
    int b = bh >> 2, h = bh & 3;
    int t = threadIdx.x, w = t >> 6, l = t & 63, lr = l & 15, lg = l >> 4;

    bf16x8 aq[4];
#pragma unroll
    for (int f = 0; f < 4; ++f)
        aq[f] = *(const bf16x8*)(qt + ((size_t)bh * N_ + n0 + 16 * f + lr) * KD_ + 8 * lg);

    // staging: wave w stages K rows [16w,16w+16), V rows [16w,16w+16) of each half
    int krow = 16 * w + (l >> 2);
    const bf16* kg = kt + ((size_t)bh * N_ + krow) * KD_ + 8 * (l & 3);
    int fkr = (krow ^ (krow >> 2)) & 3;
    int kwo = krow * KD_ + 8 * ((l & 3) ^ fkr);
    int vrow0 = 16 * w + (l >> 3), vrow1 = vrow0 + 8;
    const bf16* vg0 = vb + ((size_t)bh * HD_ + vrow0) * N_ + 8 * (l & 7);
    const bf16* vg1 = vb + ((size_t)bh * HD_ + vrow1) * N_ + 8 * (l & 7);
    int vwo0 = vrow0 * 64 + 8 * ((l & 7) ^ (vrow0 & 7));
    int vwo1 = vrow1 * 64 + 8 * ((l & 7) ^ (vrow1 & 7));

    // read offsets (wave-local slices, per half)
    int kro = (16 * w + lr) * KD_ + 8 * (lg ^ ((lr ^ (lr >> 2)) & 3));
    int vro = 8 * ((2 * w + (lg >> 1)) ^ (lr & 7)) + 4 * ((lg & 1) ^ ((lr >> 3) & 1));

    f32x4 zz = {0.f, 0.f, 0.f, 0.f};
    f32x4 oacc[4][4];
#pragma unroll
    for (int f = 0; f < 4; ++f)
#pragma unroll
        for (int dt = 0; dt < 4; ++dt) oacc[f][dt] = zz;
    float Lp[4] = {0.f, 0.f, 0.f, 0.f};

    bf16x8 rka  = *(const bf16x8*)(kg);
    bf16x8 rkb  = *(const bf16x8*)(kg + (size_t)64 * KD_);
    bf16x8 rva0 = *(const bf16x8*)(vg0);
    bf16x8 rva1 = *(const bf16x8*)(vg1);
    bf16x8 rvb0 = *(const bf16x8*)(vg0 + 64);
    bf16x8 rvb1 = *(const bf16x8*)(vg1 + 64);

    int p = 0;
    for (int m0 = 0; m0 < N_; m0 += 128, p ^= 1) {
        // write both halves into parity p
        *(bf16x8*)(ldsK + p * 4096 + kwo) = rka;
        *(bf16x8*)(ldsK + p * 4096 + 2048 + kwo) = rkb;
        *(bf16x8*)(ldsV + p * 8192 + vwo0) = rva0;
        *(bf16x8*)(ldsV + p * 8192 + vwo1) =
            __builtin_shufflevector(rva1, rva1, 4, 5, 6, 7, 0, 1, 2, 3);
        *(bf16x8*)(ldsV + p * 8192 + 4096 + vwo0) = rvb0;
        *(bf16x8*)(ldsV + p * 8192 + 4096 + vwo1) =
            __builtin_shufflevector(rvb1, rvb1, 4, 5, 6, 7, 0, 1, 2, 3);
        if (m0 + 128 < N_) {
            rka  = *(const bf16x8*)(kg + (size_t)(m0 + 128) * KD_);
            rkb  = *(const bf16x8*)(kg + (size_t)(m0 + 192) * KD_);
            rva0 = *(const bf16x8*)(vg0 + m0 + 128);
            rva1 = *(const bf16x8*)(vg1 + m0 + 128);
            rvb0 = *(const bf16x8*)(vg0 + m0 + 192);
            rvb1 = *(const bf16x8*)(vg1 + m0 + 192);
        }
        __syncthreads();
#pragma unroll
        for (int hf = 0; hf < 2; ++hf) {
            bf16x8 kf = *(const bf16x8*)(ldsK + p * 4096 + hf * 2048 + kro);
            bf16x4 vf[4];
#pragma unroll
            for (int dt = 0; dt < 4; ++dt)
                vf[dt] = *(const bf16x4*)(ldsV + p * 8192 + hf * 4096 + (16 * dt + lr) * 64 + vro);
#pragma unroll
            for (int f = 0; f < 4; ++f) {
                f32x4 s = __builtin_amdgcn_mfma_f32_16x16x32_bf16(kf, aq[f], zz, 0, 0, 0);
                f32x4 pv;
#pragma unroll
                for (int j = 0; j < 4; ++j) pv[j] = __builtin_amdgcn_exp2f(s[j]);
                Lp[f] += (pv[0] + pv[1]) + (pv[2] + pv[3]);
                bf16x4 pk;
#pragma unroll
                for (int j = 0; j < 4; ++j) pk[j] = (bf16)pv[j];
                asm("s_nop 1\n\t"
                    "v_mfma_f32_16x16x16_bf16 %0, %4, %5, %0\n\t"
                    "v_mfma_f32_16x16x16_bf16 %1, %4, %6, %1\n\t"
                    "v_mfma_f32_16x16x16_bf16 %2, %4, %7, %2\n\t"
                    "v_mfma_f32_16x16x16_bf16 %3, %4, %8, %3"
                    : "+v"(oacc[f][0]), "+v"(oacc[f][1]), "+v"(oacc[f][2]), "+v"(oacc[f][3])
                    : "v"(pk), "v"(vf[0]), "v"(vf[1]), "v"(vf[2]), "v"(vf[3]));
            }
        }
    }
    // MFMA(asm) -> VALU/LDS read hazard guard
    asm volatile("s_nop 7\n\ts_nop 7\n\ts_nop 7" ::: "memory");
    __syncthreads();   // guard: red/vt alias K/V — all waves done with main loop

    // ---- L reduce: over lg (shfl), then over waves (LDS) ----
#pragma unroll
    for (int f = 0; f < 4; ++f) {
        Lp[f] += __shfl_xor(Lp[f], 16);
        Lp[f] += __shfl_xor(Lp[f], 32);
    }
    if (lg == 0) {
#pragma unroll
        for (int f = 0; f < 4; ++f) red[w * 64 + 16 * f + lr] = Lp[f];
    }
    __syncthreads();
    float invL[4];
#pragma unroll
    for (int f = 0; f < 4; ++f) {
        float Lt = red[16 * f + lr] + red[64 + 16 * f + lr] +
                   red[128 + 16 * f + lr] + red[192 + 16 * f + lr];
        invL[f] = 1.f / Lt;
    }
    __syncthreads();

    // ---- O cross-wave reduce: 4 static passes over dt; register indices static ----
    f32x4 ofin[4];
#pragma unroll
    for (int f = 0; f < 4; ++f) ofin[f] = zz;
#pragma unroll
    for (int dt = 0; dt < 4; ++dt) {
#pragma unroll
        for (int f = 0; f < 4; ++f)
#pragma unroll
            for (int j = 0; j < 4; ++j)
                red[w * 1024 + (16 * f + 4 * lg + j) * 16 + lr] = oacc[f][dt][j];
        __syncthreads();
        if (w == dt) {
#pragma unroll
            for (int f = 0; f < 4; ++f)
#pragma unroll
                for (int j = 0; j < 4; ++j) {
                    int idx = (16 * f + 4 * lg + j) * 16 + lr;
                    ofin[f][j] = red[idx] + red[1024 + idx] + red[2048 + idx] + red[3072 + idx];
                }
        }
        __syncthreads();
    }

    // ---- fused PE: stage v window (rows hh-1..hh+1, 64 ch) into vt, stride 200 ----
    {
        bf16x8 zero8 = {};
#pragma unroll
        for (int i = 0; i < 6; ++i) {
            int pair = (t >> 3) + 32 * i;     // 0..191
            int d = pair & 63, kh = pair >> 6;
            int hh2 = hh + kh - 1;
            bf16x8 val = zero8;
            if (hh2 >= 0 && hh2 < 64)
                val = *(const bf16x8*)(vb + ((size_t)bh * HD_ + d) * N_ + hh2 * 64 + (t & 7) * 8);
            *(bf16x8*)(vt + d * 200 + kh * 64 + (t & 7) * 8) = val;
        }
    }
    __syncthreads();

    // ---- conv + normalize + store: thread owns d=16w+lr, n = n0 + 16f + 4lg + j ----
    int dloc = 16 * w + lr;
    int c = h * 64 + dloc;
    float w9[9];
#pragma unroll
    for (int k = 0; k < 9; ++k) w9[k] = wpe[c * 9 + k];
    float bc = bpe[c];
#pragma unroll
    for (int f = 0; f < 4; ++f) {
        float conv[4] = {bc, bc, bc, bc};
#pragma unroll
        for (int kh = 0; kh < 3; ++kh) {
            float tv[6];
#pragma unroll
            for (int s = 0; s < 6; ++s) {
                int q = 16 * f + 4 * lg - 1 + s;
                tv[s] = (q >= 0 && q < 64) ? (float)vt[dloc * 200 + kh * 64 + q] : 0.f;
            }
#pragma unroll
            for (int j = 0; j < 4; ++j)
                conv[j] += tv[j] * w9[kh * 3] + tv[j + 1] * w9[kh * 3 + 1] + tv[j + 2] * w9[kh * 3 + 2];
        }
#pragma unroll
        for (int j = 0; j < 4; ++j) {
            float iv = __shfl(invL[f], 4 * lg + j);
            int n = n0 + 16 * f + 4 * lg + j;
            yT[((size_t)b * N_ + n) * C_ + c] = (bf16)(ofin[f][j] * iv + conv[j]);
        }
    }
}

// ---------------- proj GEMM + residual -> x2 (bf16) + fused CA partial sum/max ----------------
__global__ __launch_bounds__(256) void k_proj(const bf16* __restrict__ wpb,
                                              const bf16* __restrict__ yT,
                                              const float* __restrict__ bias,
                                              const float* __restrict__ x,
                                              bf16* __restrict__ x2,
                                              float* __restrict__ psum,
                                              float* __restrict__ pmax) {
    int n0 = blockIdx.x * 64, o0 = blockIdx.y * 64, b = blockIdx.z;
    int t = threadIdx.x, w = t >> 6, l = t & 63, lr = l & 15, lg = l >> 4;
    const bf16* arow = wpb + (size_t)(o0 + 16 * w + lr) * C_ + 8 * lg;
    const bf16* brow = yT + ((size_t)b * N_ + n0 + lr) * C_ + 8 * lg;
    f32x4 acc[4];
    f32x4 zz = {0.f, 0.f, 0.f, 0.f};
    acc[0] = zz; acc[1] = zz; acc[2] = zz; acc[3] = zz;
    for (int kk = 0; kk < C_; kk += 32) {
        bf16x8 a = *(const bf16x8*)(arow + kk);
#pragma unroll
        for (int tt = 0; tt < 4; ++tt) {
            bf16x8 bb = *(const bf16x8*)(brow + (size_t)tt * 16 * C_ + kk);
            acc[tt] = __builtin_amdgcn_mfma_f32_16x16x32_bf16(a, bb, acc[tt], 0, 0, 0);
        }
    }
    float lsum[4] = {0.f, 0.f, 0.f, 0.f};
    float lmax[4] = {-1e30f, -1e30f, -1e30f, -1e30f};
#pragma unroll
    for (int tt = 0; tt < 4; ++tt) {
        int n = n0 + 16 * tt + lr;
#pragma unroll
        for (int j = 0; j < 4; ++j) {
            int o = o0 + 16 * w + 4 * lg + j;
            size_t idx = ((size_t)b * C_ + o) * N_ + n;
            float v = x[idx] + acc[tt][j] + bias[o];
            x2[idx] = (bf16)v;
            lsum[j] += v;
            lmax[j] = fmaxf(lmax[j], v);
        }
    }
#pragma unroll
    for (int d = 1; d < 16; d <<= 1) {
#pragma unroll
        for (int j = 0; j < 4; ++j) {
            lsum[j] += __shfl_xor(lsum[j], d);
            lmax[j] = fmaxf(lmax[j], __shfl_xor(lmax[j], d));
        }
    }
    if (lr == 0) {
#pragma unroll
        for (int j = 0; j < 4; ++j) {
            int o = o0 + 16 * w + 4 * lg + j;
            size_t pidx = ((size_t)(b * C_ + o)) * 64 + blockIdx.x;
            psum[pidx] = lsum[j];
            pmax[pidx] = lmax[j];
        }
    }
}

// ---------------- channel attention finish: reduce partials + MLP + sigmoid ----------------
__global__ __launch_bounds__(256) void k_ca_fin(const float* __restrict__ psum,
                                                const float* __restrict__ pmax,
                                                const float* __restrict__ wfc1,
                                                const float* __restrict__ wfc2,
                                                float* __restrict__ ca) {
    int b = blockIdx.x, t = threadIdx.x;  // t = channel
    const float* ps = psum + ((size_t)(b * C_ + t)) * 64;
    const float* pm = pmax + ((size_t)(b * C_ + t)) * 64;
    float s = 0.f, m = -1e30f;
#pragma unroll 8
    for (int i = 0; i < 64; ++i) { s += ps[i]; m = fmaxf(m, pm[i]); }
    __shared__ float sav[C_], smx[C_];
    sav[t] = s * (1.f / (float)N_);
    smx[t] = m;
    __syncthreads();
    __shared__ float hsum[16];
    if (t < 16) {
        const float* w1 = wfc1 + t * C_;
        float ha = 0.f, hm = 0.f;
        for (int c = 0; c < C_; ++c) { ha += sav[c] * w1[c]; hm += smx[c] * w1[c]; }
        hsum[t] = fmaxf(ha, 0.f) + fmaxf(hm, 0.f);
    }
    __syncthreads();
    float o = 0.f;
    const float* w2 = wfc2 + t * 16;
#pragma unroll
    for (int r = 0; r < 16; ++r) o += hsum[r] * w2[r];
    ca[b * C_ + t] = 1.f / (1.f + __expf(-o));
}

// ---------------- spatial attention: channel reduce of x2*ca, 4-way c-split ----------------
__global__ __launch_bounds__(256) void k_sa_red(const bf16* __restrict__ x2,
                                                const float* __restrict__ ca,
                                                float* __restrict__ sain) {
    int b = blockIdx.y;
    int n0 = blockIdx.x * 64;
    int t = threadIdx.x, nl = t & 63, cg = t >> 6;
    __shared__ float cal[C_];
    cal[t] = ca[b * C_ + t];
    __syncthreads();
    int n = n0 + nl;
    float s = 0.f, m = -1e30f;
#pragma unroll 8
    for (int ci = 0; ci < 64; ++ci) {
        int c = cg * 64 + ci;
        float v = (float)x2[((size_t)b * C_ + c) * N_ + n] * cal[c];
        s += v; m = fmaxf(m, v);
    }
    __shared__ float ps[4][64], pm[4][64];
    ps[cg][nl] = s; pm[cg][nl] = m;
    __syncthreads();
    if (t < 64) {
        float ss = ps[0][t] + ps[1][t] + ps[2][t] + ps[3][t];
        float mm = fmaxf(fmaxf(pm[0][t], pm[1][t]), fmaxf(pm[2][t], pm[3][t]));
        sain[((size_t)b * 2 + 0) * N_ + n0 + t] = ss * (1.f / C_);
        sain[((size_t)b * 2 + 1) * N_ + n0 + t] = mm;
    }
}

// ---------------- final: sa conv + sigmoid + output (f32), 4-way c-split ----------------
__global__ __launch_bounds__(256) void k_final(const bf16* __restrict__ x2,
                                               const float* __restrict__ ca,
                                               const float* __restrict__ sain,
                                               const float* __restrict__ wsa,
                                               float* __restrict__ out) {
    int b = blockIdx.z;
    int c0 = blockIdx.y * 64;
    int n = blockIdx.x * 256 + threadIdx.x;
    __shared__ float cal[64];
    if (threadIdx.x < 64) cal[threadIdx.x] = ca[b * C_ + c0 + threadIdx.x];
    __syncthreads();
    int hh = n >> 6, ww = n & 63;
    float acc = 0.f;
#pragma unroll
    for (int i = 0; i < 2; ++i)
#pragma unroll
        for (int kh = 0; kh < 3; ++kh) {
            int hh2 = hh + kh - 1;
            if (hh2 < 0 || hh2 >= 64) continue;
#pragma unroll
            for (int kw = 0; kw < 3; ++kw) {
                int ww2 = ww + kw - 1;
                if (ww2 < 0 || ww2 >= 64) continue;
                acc += sain[((size_t)b * 2 + i) * N_ + hh2 * 64 + ww2] * wsa[i * 9 + kh * 3 + kw];
            }
        }
    float sa = 1.f / (1.f + __expf(-acc));
#pragma unroll 8
    for (int ci = 0; ci < 64; ++ci) {
        int c = c0 + ci;
        size_t idx = ((size_t)b * C_ + c) * N_ + n;
        out[idx] = (float)x2[idx] * cal[ci] * sa;
    }
}

extern "C" void kernel_launch(void* const* d_in, const int* in_sizes, int n_in,
                              void* d_out, int out_size, void* d_ws, size_t ws_size,
                              hipStream_t stream) {
    const float* x     = (const float*)d_in[0];
    const float* wqkv  = (const float*)d_in[1];
    const float* bqkv  = (const float*)d_in[2];
    const float* wproj = (const float*)d_in[3];
    const float* bproj = (const float*)d_in[4];
    const float* wpe   = (const float*)d_in[5];
    const float* bpe   = (const float*)d_in[6];
    const float* wfc1  = (const float*)d_in[7];
    const float* wfc2  = (const float*)d_in[8];
    const float* wsa   = (const float*)d_in[9];
    float* out = (float*)d_out;

    char* ws = (char*)d_ws;
    size_t off = 0;
    auto alloc = [&](size_t bytes) {
        char* p = ws + off;
        off += (bytes + 255) & ~(size_t)255;
        return p;
    };
    bf16*  qt    = (bf16*)alloc((size_t)B_ * NH_ * N_ * KD_ * 2);
    bf16*  ktb   = (bf16*)alloc((size_t)B_ * NH_ * N_ * KD_ * 2);
    bf16*  vbuf  = (bf16*)alloc((size_t)B_ * NH_ * HD_ * N_ * 2);
    bf16*  xT    = (bf16*)alloc((size_t)B_ * N_ * C_ * 2);
    bf16*  x2    = (bf16*)alloc((size_t)B_ * C_ * N_ * 2);
    bf16*  wqb   = (bf16*)alloc((size_t)HQKV_ * C_ * 2);
    bf16*  wpb   = (bf16*)alloc((size_t)C_ * C_ * 2);
    float* psum  = (float*)alloc((size_t)B_ * C_ * 64 * 4);
    float* pmax  = (float*)alloc((size_t)B_ * C_ * 64 * 4);
    float* cab   = (float*)alloc(B_ * C_ * 4);
    float* sain  = (float*)alloc((size_t)B_ * 2 * N_ * 4);
    bf16*  yT    = xT;  // alias: xT dead after k_qkv completes (stream-ordered)

    k_prep<<<dim3(64, 4, B_), 256, 0, stream>>>(x, xT, wqkv, wproj, wqb, wpb);
    k_qkv<<<dim3(64, 8, B_), 256, 0, stream>>>(wqb, xT, bqkv, qt, ktb, vbuf);
    k_attn<<<dim3(1024), 256, 0, stream>>>(qt, ktb, vbuf, wpe, bpe, yT);
    k_proj<<<dim3(64, 4, B_), 256, 0, stream>>>(wpb, yT, bproj, x, x2, psum, pmax);
    k_ca_fin<<<dim3(B_), 256, 0, stream>>>(psum, pmax, wfc1, wfc2, cab);
    k_sa_red<<<dim3(64, B_), 256, 0, stream>>>(x2, cab, sain);
    k_final<<<dim3(16, 4, B_), 256, 0, stream>>>(x2, cab, sain, wsa, out);
}